// Round 11
// baseline (54.152 us; speedup 1.0000x reference)
//
#include <hip/hip_runtime.h>
#include <hip/hip_cooperative_groups.h>
#include <math.h>

namespace cg = cooperative_groups;

#define N_IN   2048
#define N_OUT  2048
#define BATCH  64
#define NEG_FILL (-1e9f)
#define TEMP   0.1f
#define INV_TEMP 10.0f
#define NBLK   256       // 256 blocks x 1024 thr: <= co-resident capacity (2048 thr/CU)
#define ROWS_PB 8        // 256 * 8 = 2048 output rows
#define MAXH   64        // max nz per half-row (mean 7.5)

// ws layout (floats): [0..63] row sums, [64..127] row absmax, [128..] xT[2048][64]
#define WS_XT_OFF 128

// ---------------------------------------------------------------------------
// ONE cooperative dispatch. 256 blocks x 1024 threads (16 waves).
//  pre-sync (tiny, ~0.5MB):
//    blocks 0..63  : row-stats (sum, absmax) of x row blk -> ws[0..127]
//    blocks 64..95 : LDS-tiled transpose of a 64-wide i-tile into xT[i][b]
//    blocks 96..255: nothing (arrive at barrier instantly)
//  grid.sync()  (cooperative-groups; the sanctioned barrier)
//  post-sync (the bulk, full-grid width):
//    wave wv ballot-compacts mask half-row (row o0+(wv>>1), half wv&1) into a
//    wave-private LDS CSR (idx, ew=exp(w/T)); immediately dots it against xT
//    (lane = batch, coalesced 256B column reads, L2-hot); halves merge by
//    addition in LDS; T*log; staged 32B-contiguous write of out[:, o0..o0+7].
// ---------------------------------------------------------------------------
__global__ __launch_bounds__(1024) void fused_kernel(const float* __restrict__ x,
                                                     const float* __restrict__ w,
                                                     const float* __restrict__ mask,
                                                     float* __restrict__ ws,
                                                     float* __restrict__ out) {
    const int tid  = threadIdx.x;
    const int wv   = tid >> 6;          // 0..15
    const int lane = tid & 63;
    const int blk  = blockIdx.x;
    const int o0   = blk * ROWS_PB;

    __shared__ int   s_idx[16][MAXH];
    __shared__ float s_ew [16][MAXH];
    __shared__ int   s_cnt[16];
    __shared__ float s_acc[16][BATCH];
    __shared__ float s_res[ROWS_PB][BATCH + 1];
    __shared__ float t[64][65];         // transpose tile / stats partials (t[0][*])
    __shared__ float s_red[16];

    // ---------------- pre-sync prep (blocks 0..95 only) ---------------------
    if (blk < 64) {
        // row-stats of x row `blk`: threads 0..511 read one float4 each
        float sum = 0.f, amax = 0.f;
        if (tid < 512) {
            const float4 v = reinterpret_cast<const float4*>(x + (size_t)blk * N_IN)[tid];
            sum  = v.x + v.y + v.z + v.w;
            amax = fmaxf(fmaxf(fabsf(v.x), fabsf(v.y)), fmaxf(fabsf(v.z), fabsf(v.w)));
        }
        for (int off = 32; off; off >>= 1) {
            sum += __shfl_xor(sum, off);
            amax = fmaxf(amax, __shfl_xor(amax, off));
        }
        if (lane == 0) { s_red[wv] = sum; t[0][wv] = amax; }
        __syncthreads();
        if (tid == 0) {
            float s = 0.f, m = 0.f;
#pragma unroll
            for (int i = 0; i < 8; ++i) { s += s_red[i]; m = fmaxf(m, t[0][i]); }
            ws[blk]         = s;
            ws[BATCH + blk] = m;
        }
        __syncthreads();
    } else if (blk < 96) {
        // transpose a 64-wide i-tile: coalesced read + coalesced write via LDS
        const int i0 = (blk - 64) * 64;
        float* xT = ws + WS_XT_OFF;
#pragma unroll
        for (int r = 0; r < 4; ++r) {
            const int b = wv * 4 + r;           // wv 0..15 -> rows 0..63
            t[lane][b] = x[(size_t)b * N_IN + i0 + lane];
        }
        __syncthreads();
#pragma unroll
        for (int r = 0; r < 4; ++r) {
            const int i_l = wv * 4 + r;
            xT[(size_t)(i0 + i_l) * 64 + lane] = t[i_l][lane];
        }
    }

    // ---------------- grid-wide sync (cooperative groups) -------------------
    cg::this_grid().sync();

    // ---------------- stats finalize (wave-redundant, 512B L2 reads) --------
    const float sum_l = ws[lane];
    float mx = ws[BATCH + lane];
    for (int off = 32; off; off >>= 1) mx = fmaxf(mx, __shfl_xor(mx, off));
    const float dinv = 1.0f / (mx + 1e-6f);
    const float cons = sum_l * dinv * (1.0f / (float)N_IN);   // lane = batch

    // ---------------- ballot compaction of this wave's half-row -------------
    const int row = o0 + (wv >> 1);
    const int hh  = wv & 1;
    const float4* mrow = reinterpret_cast<const float4*>(mask + (size_t)row * N_IN) + hh * 256;
    const float*  wrow = w + (size_t)row * N_IN;
    const int     ih0  = hh * 1024;
    const unsigned long long below = (1ull << lane) - 1ull;
    int cnt = 0;
#pragma unroll
    for (int r = 0; r < 4; ++r) {
        const float4 mv = mrow[r * 64 + lane];
        const int base  = ih0 + (r * 64 + lane) * 4;
        {
            const bool f = (mv.x != 0.f);
            const unsigned long long bal = __ballot(f);
            if (f) { int p = cnt + __popcll(bal & below);
                     if (p < MAXH) { s_idx[wv][p] = base + 0;
                                     s_ew[wv][p]  = __expf(wrow[base + 0] * INV_TEMP); } }
            cnt += __popcll(bal);
        }
        {
            const bool f = (mv.y != 0.f);
            const unsigned long long bal = __ballot(f);
            if (f) { int p = cnt + __popcll(bal & below);
                     if (p < MAXH) { s_idx[wv][p] = base + 1;
                                     s_ew[wv][p]  = __expf(wrow[base + 1] * INV_TEMP); } }
            cnt += __popcll(bal);
        }
        {
            const bool f = (mv.z != 0.f);
            const unsigned long long bal = __ballot(f);
            if (f) { int p = cnt + __popcll(bal & below);
                     if (p < MAXH) { s_idx[wv][p] = base + 2;
                                     s_ew[wv][p]  = __expf(wrow[base + 2] * INV_TEMP); } }
            cnt += __popcll(bal);
        }
        {
            const bool f = (mv.w != 0.f);
            const unsigned long long bal = __ballot(f);
            if (f) { int p = cnt + __popcll(bal & below);
                     if (p < MAXH) { s_idx[wv][p] = base + 3;
                                     s_ew[wv][p]  = __expf(wrow[base + 3] * INV_TEMP); } }
            cnt += __popcll(bal);
        }
    }
    cnt = min(cnt, MAXH);
    if (lane == 0) s_cnt[wv] = cnt;

    // ---------------- sparse dot (lane = batch, xT columns L2-hot) ----------
    const float* xT = ws + WS_XT_OFF;
    float acc = 0.f;
    int k = 0;
    for (; k + 2 <= cnt; k += 2) {
        const int   i0_ = s_idx[wv][k + 0], i1_ = s_idx[wv][k + 1];
        const float e0  = s_ew[wv][k + 0],  e1  = s_ew[wv][k + 1];
        const float v0  = xT[(size_t)i0_ * 64 + lane] * dinv;
        const float v1  = xT[(size_t)i1_ * 64 + lane] * dinv;
        const float g0  = (fabsf(v0 - cons) < 1.0f) ? v0 : 0.f;
        const float g1  = (fabsf(v1 - cons) < 1.0f) ? v1 : 0.f;
        acc += e0 * __expf(g0 * INV_TEMP);
        acc += e1 * __expf(g1 * INV_TEMP);
    }
    if (k < cnt) {
        const int   i_ = s_idx[wv][k];
        const float e_ = s_ew[wv][k];
        const float v  = xT[(size_t)i_ * 64 + lane] * dinv;
        const float g  = (fabsf(v - cons) < 1.0f) ? v : 0.f;
        acc += e_ * __expf(g * INV_TEMP);
    }

    // ---------------- merge halves, log, staged write -----------------------
    s_acc[wv][lane] = acc;
    __syncthreads();
    if (hh == 0) {
        const float total = s_acc[wv][lane] + s_acc[wv + 1][lane];
        const int   tcnt  = s_cnt[wv] + s_cnt[wv + 1];
        const float res   = (tcnt > 0) ? TEMP * logf(total)
                                       : NEG_FILL + TEMP * logf((float)N_IN);
        s_res[wv >> 1][lane] = res;
    }
    __syncthreads();
    if (tid < 512) {
        const int b = tid >> 3, c = tid & 7;   // 32B contiguous per batch
        out[(size_t)b * N_OUT + o0 + c] = s_res[c][b];
    }
}

extern "C" void kernel_launch(void* const* d_in, const int* in_sizes, int n_in,
                              void* d_out, int out_size, void* d_ws, size_t ws_size,
                              hipStream_t stream) {
    const float* x    = (const float*)d_in[0];
    const float* wgt  = (const float*)d_in[1];
    const float* mask = (const float*)d_in[2];
    float* out = (float*)d_out;
    float* ws  = (float*)d_ws;   // 128 + 2048*64 floats

    void* args[] = { (void*)&x, (void*)&wgt, (void*)&mask, (void*)&ws, (void*)&out };
    hipLaunchCooperativeKernel((void*)fused_kernel, dim3(NBLK), dim3(1024),
                               args, 0, stream);
}

// Round 12
// 21.669 us; speedup vs baseline: 2.4991x; 2.4991x over previous
//
#include <hip/hip_runtime.h>
#include <math.h>

#define N_IN   2048
#define N_OUT  2048
#define BATCH  64
#define NEG_FILL (-1e9f)
#define TEMP   0.1f
#define INV_TEMP 10.0f
#define NBLK   256       // 2048 rows / 8 rows per block; 1 block/CU
#define ROWS_PB 8
#define MAXH   64        // max nz per half-row (mean 7.5)
#define MAXSLOTS 192     // max distinct columns per block (mean ~120)

// ---------------------------------------------------------------------------
// Single fused kernel, one dispatch, no grid sync, no workspace.
// 256 blocks x 1024 threads (16 waves).  Differs from R9 ONLY in load
// structure: all memory loads are hoisted/batched ahead of dependent ALU so
// each phase's chain depth is ~2 memory rounds instead of ~16.
//  A : wave wv: load 4 mask float4 (independent) -> regs; issue <=4
//      exec-masked float4 w-loads (addresses depend only on mask); THEN
//      exps + ballot bookkeeping (pure ALU) into LDS CSR (idx, ew).
//  A2: dedup block's columns into slots (LDS atomicCAS + counter).
//  C : wave wv streams x rows 4wv..4wv+3 (8 indep float4 per row):
//      row sum/absmax (shfl reduce) + scatter needed cols into s_xg.
//  D : per-wave sparse dot from LDS (lane = batch), halves merge, log,
//      staged 32B-contiguous write.
// ---------------------------------------------------------------------------
__global__ __launch_bounds__(1024) void fused_kernel(const float* __restrict__ x,
                                                     const float* __restrict__ w,
                                                     const float* __restrict__ mask,
                                                     float* __restrict__ out) {
    const int tid  = threadIdx.x;
    const int wv   = tid >> 6;          // 0..15
    const int lane = tid & 63;
    const int blk  = blockIdx.x;
    const int o0   = blk * ROWS_PB;

    __shared__ int   s_idx[16][MAXH];
    __shared__ float s_ew [16][MAXH];
    __shared__ int   s_cnt[16];
    __shared__ int   s_col2slot[N_IN];
    __shared__ int   s_nslots;
    __shared__ float s_xg[MAXSLOTS][BATCH];
    __shared__ float s_rsum[BATCH];
    __shared__ float s_ramax[BATCH];
    __shared__ float s_acc[16][BATCH];
    __shared__ float s_res[ROWS_PB][BATCH + 1];

    // ---------------- init --------------------------------------------------
    s_col2slot[tid]        = -1;
    s_col2slot[tid + 1024] = -1;
    if (tid == 0) s_nslots = 0;

    // ---------------- phase A: batched loads, then compaction ---------------
    const int row = o0 + (wv >> 1);
    const int hh  = wv & 1;
    const float4* mrow = reinterpret_cast<const float4*>(mask + (size_t)row * N_IN) + hh * 256;
    const float4* wrow4 = reinterpret_cast<const float4*>(w + (size_t)row * N_IN) + hh * 256;
    const int     ih0  = hh * 1024;

    // 1) all mask loads up front (independent)
    float4 mv[4];
#pragma unroll
    for (int r = 0; r < 4; ++r) mv[r] = mrow[r * 64 + lane];

    // 2) exec-masked vector w loads (addresses independent of compaction)
    float4 wl[4];
#pragma unroll
    for (int r = 0; r < 4; ++r) {
        const bool any = (mv[r].x != 0.f) | (mv[r].y != 0.f) |
                         (mv[r].z != 0.f) | (mv[r].w != 0.f);
        if (any) wl[r] = wrow4[r * 64 + lane];
    }

    // 3) pure-ALU ballot bookkeeping + stores
    const unsigned long long below = (1ull << lane) - 1ull;
    int cnt = 0;
#pragma unroll
    for (int r = 0; r < 4; ++r) {
        const int base = ih0 + (r * 64 + lane) * 4;
        const float wf[4] = { wl[r].x, wl[r].y, wl[r].z, wl[r].w };
        const float mf[4] = { mv[r].x, mv[r].y, mv[r].z, mv[r].w };
#pragma unroll
        for (int j = 0; j < 4; ++j) {
            const bool f = (mf[j] != 0.f);
            const unsigned long long bal = __ballot(f);
            if (f) {
                const int p = cnt + __popcll(bal & below);
                if (p < MAXH) {
                    s_idx[wv][p] = base + j;
                    s_ew[wv][p]  = __expf(wf[j] * INV_TEMP);
                }
            }
            cnt += __popcll(bal);
        }
    }
    cnt = min(cnt, MAXH);
    if (lane == 0) s_cnt[wv] = cnt;
    __syncthreads();   // col2slot init + compaction visible

    // ---------------- A2: dedup slot assignment -----------------------------
    if (lane < cnt) {
        const int c = s_idx[wv][lane];
        if (atomicCAS(&s_col2slot[c], -1, -2) == -1) {
            const int sl = atomicAdd(&s_nslots, 1);
            s_col2slot[c] = sl;
        }
    }
    __syncthreads();

    // ---------------- phase C: stream x — stats + scatter -------------------
    const int4* slot4 = reinterpret_cast<const int4*>(s_col2slot);
#pragma unroll
    for (int r = 0; r < 4; ++r) {
        const int b = wv * 4 + r;
        const float4* xr = reinterpret_cast<const float4*>(x + (size_t)b * N_IN);
        // batched independent loads for this row
        float4 xv[8];
#pragma unroll
        for (int it = 0; it < 8; ++it) xv[it] = xr[it * 64 + lane];
        float sum = 0.f, amax = 0.f;
#pragma unroll
        for (int it = 0; it < 8; ++it) {
            const float4 v  = xv[it];
            const int4  sl4 = slot4[it * 64 + lane];
            sum += v.x + v.y + v.z + v.w;
            amax = fmaxf(amax, fmaxf(fmaxf(fabsf(v.x), fabsf(v.y)),
                                     fmaxf(fabsf(v.z), fabsf(v.w))));
            if (sl4.x >= 0 && sl4.x < MAXSLOTS) s_xg[sl4.x][b] = v.x;
            if (sl4.y >= 0 && sl4.y < MAXSLOTS) s_xg[sl4.y][b] = v.y;
            if (sl4.z >= 0 && sl4.z < MAXSLOTS) s_xg[sl4.z][b] = v.z;
            if (sl4.w >= 0 && sl4.w < MAXSLOTS) s_xg[sl4.w][b] = v.w;
        }
        for (int off = 32; off; off >>= 1) {
            sum += __shfl_xor(sum, off);
            amax = fmaxf(amax, __shfl_xor(amax, off));
        }
        if (lane == 0) { s_rsum[b] = sum; s_ramax[b] = amax; }
    }
    __syncthreads();

    // ---------------- stats finalize (wave-redundant) -----------------------
    float mx = s_ramax[lane];
    for (int off = 32; off; off >>= 1) mx = fmaxf(mx, __shfl_xor(mx, off));
    const float dinv = 1.0f / (mx + 1e-6f);
    const float cons = s_rsum[lane] * dinv * (1.0f / (float)N_IN);   // lane = batch

    // ---------------- phase D: sparse dot from LDS (lane = batch) -----------
    const float* xrow = x + (size_t)lane * N_IN;   // fallback only (slot overflow)
    float acc = 0.f;
    int k = 0;
    for (; k + 2 <= cnt; k += 2) {
        const int   c0 = s_idx[wv][k + 0], c1 = s_idx[wv][k + 1];
        const float e0 = s_ew[wv][k + 0],  e1 = s_ew[wv][k + 1];
        const int   sl0 = s_col2slot[c0],  sl1 = s_col2slot[c1];
        const float x0 = (sl0 < MAXSLOTS) ? s_xg[sl0][lane] : xrow[c0];
        const float x1 = (sl1 < MAXSLOTS) ? s_xg[sl1][lane] : xrow[c1];
        const float v0 = x0 * dinv;
        const float v1 = x1 * dinv;
        const float g0 = (fabsf(v0 - cons) < 1.0f) ? v0 : 0.f;
        const float g1 = (fabsf(v1 - cons) < 1.0f) ? v1 : 0.f;
        acc += e0 * __expf(g0 * INV_TEMP);
        acc += e1 * __expf(g1 * INV_TEMP);
    }
    if (k < cnt) {
        const int   c_ = s_idx[wv][k];
        const float e_ = s_ew[wv][k];
        const int   sl = s_col2slot[c_];
        const float xv = (sl < MAXSLOTS) ? s_xg[sl][lane] : xrow[c_];
        const float v  = xv * dinv;
        const float g  = (fabsf(v - cons) < 1.0f) ? v : 0.f;
        acc += e_ * __expf(g * INV_TEMP);
    }

    s_acc[wv][lane] = acc;
    __syncthreads();
    if (hh == 0) {
        const float total = s_acc[wv][lane] + s_acc[wv + 1][lane];
        const int   tcnt  = s_cnt[wv] + s_cnt[wv + 1];
        const float res   = (tcnt > 0) ? TEMP * logf(total)
                                       : NEG_FILL + TEMP * logf((float)N_IN);
        s_res[wv >> 1][lane] = res;
    }
    __syncthreads();
    if (tid < 512) {
        const int b = tid >> 3, c = tid & 7;   // 32B contiguous per batch
        out[(size_t)b * N_OUT + o0 + c] = s_res[c][b];
    }
}

extern "C" void kernel_launch(void* const* d_in, const int* in_sizes, int n_in,
                              void* d_out, int out_size, void* d_ws, size_t ws_size,
                              hipStream_t stream) {
    const float* x    = (const float*)d_in[0];
    const float* wgt  = (const float*)d_in[1];
    const float* mask = (const float*)d_in[2];
    float* out = (float*)d_out;
    (void)d_ws; (void)ws_size;

    fused_kernel<<<NBLK, 1024, 0, stream>>>(x, wgt, mask, out);
}

// Round 13
// 16.391 us; speedup vs baseline: 3.3039x; 1.3220x over previous
//
#include <hip/hip_runtime.h>
#include <math.h>

#define N_IN   2048
#define N_OUT  2048
#define BATCH  64
#define NEG_FILL (-1e9f)
#define TEMP   0.1f
#define INV_TEMP 10.0f
#define MAXR   64        // max nz kept per row (mean 15, ~8 sigma margin)

// ws layout (32-bit words):
//   [0..63]      row sums of x
//   [64..127]    row absmax of x
//   WS_XT_OFF    xT[2048][64]           (x transposed)
//   WS_CNT_OFF   cnt[2048]              (int)
//   WS_PK_OFF    pack[2048][MAXR]       (float2: {bitcast idx, exp(w/T)})
#define WS_XT_OFF   128
#define WS_CNT_OFF  (WS_XT_OFF  + N_IN * BATCH)
#define WS_PK_OFF   (WS_CNT_OFF + N_OUT)          // float2 index = word/2

// ---------------------------------------------------------------------------
// Kernel 1: parallel prep, 2144 blocks x 256 threads, all-independent roles:
//   blocks 0..2047    : mask row -> packed CSR. Batched loads (2 float4 mask,
//                       then <=2 exec-masked float4 w vec-loads), THEN
//                       unordered LDS-atomic append (order-free for a sum).
//   blocks 2048..2111 : per-row sum + absmax of x row b
//   blocks 2112..2143 : transpose a 64-wide i-tile of x into xT[i][b]
// ---------------------------------------------------------------------------
__global__ __launch_bounds__(256) void prep_kernel(const float* __restrict__ x,
                                                   const float* __restrict__ w,
                                                   const float* __restrict__ mask,
                                                   float* __restrict__ ws) {
    const int tid = threadIdx.x;
    const int blk = blockIdx.x;

    __shared__ float2 s_pack[MAXR];
    __shared__ int    s_cnt;
    __shared__ float  t[64][65];
    __shared__ float  s_sum[4], s_amax[4];

    if (blk < N_OUT) {
        // ---- packed CSR compaction of mask row `blk` ----
        const int o = blk;
        if (tid == 0) s_cnt = 0;
        __syncthreads();

        const float4* mrow  = reinterpret_cast<const float4*>(mask + (size_t)o * N_IN);
        const float4* wrow4 = reinterpret_cast<const float4*>(w    + (size_t)o * N_IN);

        // 1) batched mask loads (independent)
        const float4 m0 = mrow[tid];
        const float4 m1 = mrow[tid + 256];
        // 2) exec-masked vector w loads (addresses independent of append order)
        const bool a0 = (m0.x != 0.f) | (m0.y != 0.f) | (m0.z != 0.f) | (m0.w != 0.f);
        const bool a1 = (m1.x != 0.f) | (m1.y != 0.f) | (m1.z != 0.f) | (m1.w != 0.f);
        float4 w0, w1;
        if (a0) w0 = wrow4[tid];
        if (a1) w1 = wrow4[tid + 256];
        // 3) pure-ALU append (unordered; sum is order-free)
        const int b0 = tid * 4, b1 = (tid + 256) * 4;
        if (m0.x != 0.f) { int p = atomicAdd(&s_cnt, 1); if (p < MAXR) s_pack[p] = make_float2(__int_as_float(b0 + 0), __expf(w0.x * INV_TEMP)); }
        if (m0.y != 0.f) { int p = atomicAdd(&s_cnt, 1); if (p < MAXR) s_pack[p] = make_float2(__int_as_float(b0 + 1), __expf(w0.y * INV_TEMP)); }
        if (m0.z != 0.f) { int p = atomicAdd(&s_cnt, 1); if (p < MAXR) s_pack[p] = make_float2(__int_as_float(b0 + 2), __expf(w0.z * INV_TEMP)); }
        if (m0.w != 0.f) { int p = atomicAdd(&s_cnt, 1); if (p < MAXR) s_pack[p] = make_float2(__int_as_float(b0 + 3), __expf(w0.w * INV_TEMP)); }
        if (m1.x != 0.f) { int p = atomicAdd(&s_cnt, 1); if (p < MAXR) s_pack[p] = make_float2(__int_as_float(b1 + 0), __expf(w1.x * INV_TEMP)); }
        if (m1.y != 0.f) { int p = atomicAdd(&s_cnt, 1); if (p < MAXR) s_pack[p] = make_float2(__int_as_float(b1 + 1), __expf(w1.y * INV_TEMP)); }
        if (m1.z != 0.f) { int p = atomicAdd(&s_cnt, 1); if (p < MAXR) s_pack[p] = make_float2(__int_as_float(b1 + 2), __expf(w1.z * INV_TEMP)); }
        if (m1.w != 0.f) { int p = atomicAdd(&s_cnt, 1); if (p < MAXR) s_pack[p] = make_float2(__int_as_float(b1 + 3), __expf(w1.w * INV_TEMP)); }
        __syncthreads();

        const int cnt = min(s_cnt, MAXR);
        if (tid < cnt) {
            reinterpret_cast<float2*>(ws + WS_PK_OFF)[(size_t)o * MAXR + tid] = s_pack[tid];
        }
        if (tid == 0) reinterpret_cast<int*>(ws)[WS_CNT_OFF + o] = cnt;
    } else if (blk < N_OUT + 64) {
        // ---- rowstats ----
        const int b = blk - N_OUT;
        const float4* row = reinterpret_cast<const float4*>(x + (size_t)b * N_IN);
        float sum = 0.f, amax = 0.f;
#pragma unroll
        for (int it = 0; it < 2; ++it) {
            float4 v = row[tid + it * 256];
            sum += v.x + v.y + v.z + v.w;
            amax = fmaxf(amax, fmaxf(fmaxf(fabsf(v.x), fabsf(v.y)),
                                     fmaxf(fabsf(v.z), fabsf(v.w))));
        }
        for (int off = 32; off; off >>= 1) {
            sum += __shfl_xor(sum, off);
            amax = fmaxf(amax, __shfl_xor(amax, off));
        }
        const int wid = tid >> 6;
        if ((tid & 63) == 0) { s_sum[wid] = sum; s_amax[wid] = amax; }
        __syncthreads();
        if (tid == 0) {
            ws[b]         = (s_sum[0] + s_sum[1]) + (s_sum[2] + s_sum[3]);
            ws[BATCH + b] = fmaxf(fmaxf(s_amax[0], s_amax[1]),
                                  fmaxf(s_amax[2], s_amax[3]));
        }
    } else {
        // ---- transpose tile ----
        const int i0 = (blk - N_OUT - 64) * 64;
        const int il = tid & 63;
        const int q  = tid >> 6;
        float* xT = ws + WS_XT_OFF;
#pragma unroll
        for (int r = 0; r < 16; ++r) {
            const int b = r * 4 + q;
            t[il][b] = x[(size_t)b * N_IN + i0 + il];
        }
        __syncthreads();
#pragma unroll
        for (int r = 0; r < 16; ++r) {
            const int i_l = r * 4 + q;
            xT[(size_t)(i0 + i_l) * 64 + il] = t[i_l][il];
        }
    }
}

// ---------------------------------------------------------------------------
// Kernel 2: featherweight sparse dot. 512 blocks x 256 threads (4 waves);
// wave = one output row. Lane k holds packed CSR entry k (ONE coalesced
// dwordx2 load), broadcast via __shfl; loop memory = coalesced 256B xT
// column reads (L2-hot). lane = batch. Staged 16B-chunk output.
// ---------------------------------------------------------------------------
__global__ __launch_bounds__(256) void spdot_kernel(const float* __restrict__ ws,
                                                    float* __restrict__ out) {
    const int tid  = threadIdx.x;
    const int wid  = tid >> 6;
    const int lane = tid & 63;
    const int o0   = blockIdx.x * 4;
    const int o    = o0 + wid;

    __shared__ float s_res[4][BATCH];

    // ---- stats: dinv (global), cons for this lane's batch ----
    const float sum_l = ws[lane];
    float mx = ws[BATCH + lane];
    for (int off = 32; off; off >>= 1) mx = fmaxf(mx, __shfl_xor(mx, off));
    const float dinv = 1.0f / (mx + 1e-6f);
    const float cons = sum_l * dinv * (1.0f / (float)N_IN);

    // ---- packed CSR row into registers (coalesced; lane k = entry k) ----
    const int    cnt = reinterpret_cast<const int*>(ws)[WS_CNT_OFF + o];
    const float2 myp = reinterpret_cast<const float2*>(ws + WS_PK_OFF)[(size_t)o * MAXR + lane];
    const int    myi = __float_as_int(myp.x);
    const float  mye = myp.y;
    const float* xT  = ws + WS_XT_OFF;

    float acc = 0.f;
    int k = 0;
    for (; k + 2 <= cnt; k += 2) {
        const int   i0_ = __shfl(myi, k),     i1_ = __shfl(myi, k + 1);
        const float e0  = __shfl(mye, k),     e1  = __shfl(mye, k + 1);
        const float v0  = xT[(size_t)i0_ * 64 + lane] * dinv;
        const float v1  = xT[(size_t)i1_ * 64 + lane] * dinv;
        const float g0  = (fabsf(v0 - cons) < 1.0f) ? v0 : 0.f;
        const float g1  = (fabsf(v1 - cons) < 1.0f) ? v1 : 0.f;
        acc += e0 * __expf(g0 * INV_TEMP);
        acc += e1 * __expf(g1 * INV_TEMP);
    }
    if (k < cnt) {
        const int   i_ = __shfl(myi, k);
        const float e_ = __shfl(mye, k);
        const float v  = xT[(size_t)i_ * 64 + lane] * dinv;
        const float g  = (fabsf(v - cons) < 1.0f) ? v : 0.f;
        acc += e_ * __expf(g * INV_TEMP);
    }

    const float res = (cnt > 0) ? TEMP * logf(acc)
                                : NEG_FILL + TEMP * logf((float)N_IN);
    s_res[wid][lane] = res;
    __syncthreads();

    const int b = tid >> 2, c = tid & 3;
    out[(size_t)b * N_OUT + o0 + c] = s_res[c][b];
}

extern "C" void kernel_launch(void* const* d_in, const int* in_sizes, int n_in,
                              void* d_out, int out_size, void* d_ws, size_t ws_size,
                              hipStream_t stream) {
    const float* x    = (const float*)d_in[0];
    const float* wgt  = (const float*)d_in[1];
    const float* mask = (const float*)d_in[2];
    float* out = (float*)d_out;
    float* ws  = (float*)d_ws;

    prep_kernel<<<N_OUT + 96, 256, 0, stream>>>(x, wgt, mask, ws);
    spdot_kernel<<<N_OUT / 4, 256, 0, stream>>>(ws, out);
}